// Round 9
// baseline (7210.757 us; speedup 1.0000x reference)
//
#include <hip/hip_runtime.h>
#include <stdint.h>

// Problem: D-FPS. points_xyz (16, 131072, 3) fp32 -> indices (16, 4096) int32.
//
// Round 23 = round 22 with the broadcast bug FIXED. r22 failed correctness
// (absmax 1.2e5): DPP row_bcast:15/31 fills lanes 16..63 only — w0 lanes
// 0..14 kept partial prefix-maxima and used WRONG centroids for their own
// distance phase. Fix: v_readlane_b32(k3_lo, 15) -> SGPR -> uniform widx in
// ALL w0 lanes (cheaper than the bcast chain; makes the early centroid load
// scalar-uniform). Intent of r22 kept: w0 loads the centroid BEFORE barrier2
// (overlaps bc-store + barrier, warms per-CU L1); waves 1-15 read bc after
// barrier2 and hit warm L1 (~40cy) instead of L2 (~200cy).
// Poll loop + publish byte-identical to r8/r16/r19 (6871 us best).
//
// Locked-in lessons (r2-r22):
//  - relaxed-only AGENT atomics; tag in every polled word (r7/r8).
//  - ONE relaxed polling wave per block; poll touches ONE line (r5/r10/r17).
//  - NARROW fan-in: 16 publishers; no co-residency (r15).
//  - hardware barrier beats software tag-spin for intra-block ordering (r13).
//  - DPP (VALU-pipe) reductions, never __shfl chains (r16).
//  - DPP row_bcast does NOT reach lanes below the source row (r22 bug).
//  - phase A (dist VALU + DS + reduce) is hidden under the sync chain
//    (r19/r20/r21: three big phase-A cuts, all dur-neutral).
//  - FMA-chain distance d = fma(dz,dz, fma(dy,dy, dx*dx)), subs exact-rounded
//    (r2: bit-exact vs reference trajectory).
//  - removals help; rearrangements and added traffic regress (r9-r12, r17).

#define BATCH 16
#define NPTS  131072
#define NSAMP 4096
#define NBLK  16                  // blocks per batch
#define TPB   1024                // 16 waves
#define CHUNK (NPTS / NBLK)       // 8192 points per block
#define PPT   (CHUNK / TPB)       // 8 points per thread
#define NWAVE (TPB / 64)

typedef unsigned long long u64;
typedef unsigned int u32;

// ---- DPP 64-bit lexicographic max-reduce helpers --------------------------
// key = dist_bits(32) | ~gi(32): u64 max == (max dist, then min index).
// update_dpp(old=0,...): lanes with no valid source read 0; all real keys
// are > 0, so 0 is the identity.
#define DPP_ROW_SHR(n)  (0x110 | (n))
#define DPP_BCAST15     0x142
#define DPP_BCAST31     0x143

template <int CTRL>
__device__ __forceinline__ u64 dpp_max_step(u64 key) {
    u32 lo = (u32)key, hi = (u32)(key >> 32);
    u32 olo = (u32)__builtin_amdgcn_update_dpp(0, (int)lo, CTRL, 0xF, 0xF, false);
    u32 ohi = (u32)__builtin_amdgcn_update_dpp(0, (int)hi, CTRL, 0xF, 0xF, false);
    u64 o = ((u64)ohi << 32) | (u64)olo;
    return o > key ? o : key;
}

// Full-wave (64 lane) max; result valid in lane 63.
__device__ __forceinline__ u64 dpp_max64(u64 key) {
    key = dpp_max_step<DPP_ROW_SHR(1)>(key);
    key = dpp_max_step<DPP_ROW_SHR(2)>(key);
    key = dpp_max_step<DPP_ROW_SHR(4)>(key);
    key = dpp_max_step<DPP_ROW_SHR(8)>(key);
    key = dpp_max_step<DPP_BCAST15>(key);
    key = dpp_max_step<DPP_BCAST31>(key);
    return key;
}

// Row (16 lane) max over lanes 0..15 (others must hold 0); valid in lane 15.
__device__ __forceinline__ u64 dpp_max16(u64 key) {
    key = dpp_max_step<DPP_ROW_SHR(1)>(key);
    key = dpp_max_step<DPP_ROW_SHR(2)>(key);
    key = dpp_max_step<DPP_ROW_SHR(4)>(key);
    key = dpp_max_step<DPP_ROW_SHR(8)>(key);
    return key;
}

// Global slot word (8B, one per block per parity):
//   [63:32] dist bits (>=0 -> monotone) | [31:15] idx (17b) | [14:0] iter tag
// Poison 0xAA.. -> tag 0x2AAA; zero-init -> tag 0; live tags are 1..4095.
// Ring-2 by parity; ordering via the value-dependence chain (r8-proven).

__global__ void fps_init_kernel(u64* __restrict__ ws) {
    int i = blockIdx.x * blockDim.x + threadIdx.x;
    if (i < BATCH * 2 * NBLK) ws[i] = 0ull;
}

__global__ __launch_bounds__(TPB, 4) void fps_kernel(
        const float* __restrict__ xyz, int* __restrict__ out,
        u64* __restrict__ gslot) {
    const int blk   = blockIdx.x;
    const int b     = blk & 15;    // batch: a batch's 16 blocks share blk%8
    const int chunk = blk >> 4;    //        -> same XCD (round-robin dispatch)
    const int tid   = threadIdx.x;
    const int w     = tid >> 6;
    const int lane  = tid & 63;

    const float* bxyz = xyz + (size_t)b * NPTS * 3;
    const int base = chunk * CHUNK;

    // ---- LDS: SoA points + plain red keys + plain bc (all barrier-ordered) --
    __shared__ float2 sxy[CHUNK];          // 64 KB
    __shared__ float  szz[CHUNK];          // 32 KB
    __shared__ u64 red[NWAVE];
    __shared__ u32 bc;                     // winning index, barrier-ordered
    for (int i = tid; i < CHUNK; i += TPB) {
        size_t p = (size_t)(base + i) * 3;
        sxy[i] = make_float2(bxyz[p + 0], bxyz[p + 1]);
        szz[i] = bxyz[p + 2];
    }
    if (tid == 0 && chunk == 0) out[b * NSAMP] = 0; // iter 0 emits index 0
    __syncthreads();   // staging visibility

    // ---- per-thread 8 loop-invariant points (compiler may remat from LDS;
    //      that codegen measured fastest, r19-r21) ----
    float px[PPT], py[PPT], pz[PPT], pd[PPT];
#pragma unroll
    for (int k = 0; k < PPT; ++k) {
        int i = tid + TPB * k;
        float2 xy = sxy[i];
        px[k] = xy.x;
        py[k] = xy.y;
        pz[k] = szz[i];
        pd[k] = __builtin_inff();
    }

    float cx = bxyz[0], cy = bxyz[1], cz = bxyz[2];

    u64* gs = gslot + (size_t)b * 2 * NBLK;   // [2][NBLK]

    for (int it = 1; it < NSAMP; ++it) {
        const int par = it & 1;
        u64* gsp = gs + par * NBLK;

        // ---- update min-dists + local argmax (registers) ----
        // Verified arithmetic (round 2, absmax 0): FMA-contracted
        //   d = fma(dz,dz, fma(dy,dy, dx*dx)), subs exact-rounded.
        float bd = -1.0f;
        int   bk = 0;
#pragma unroll
        for (int k = 0; k < PPT; ++k) {
            float dx = __fsub_rn(px[k], cx);
            float dy = __fsub_rn(py[k], cy);
            float dz = __fsub_rn(pz[k], cz);
            float d  = __builtin_fmaf(dz, dz,
                         __builtin_fmaf(dy, dy, __fmul_rn(dx, dx)));
            float nd = fminf(pd[k], d);
            pd[k] = nd;
            // strict >: earliest k wins (gi ascends with k) = first-occurrence
            if (nd > bd) { bd = nd; bk = k; }
        }
        u32 gi = (u32)(base + tid + TPB * bk);
        u64 key = ((u64)__float_as_uint(bd) << 32) | (u64)(~gi);

        // ---- wave max via DPP (VALU pipe) ----
        key = dpp_max64(key);              // valid in lane 63
        if (lane == 63) red[w] = key;      // plain store; barrier1 orders it
        __syncthreads();                   // barrier1

        if (w == 0) {
            // ---- combine 16 plain keys (real keys > 0; lanes 16+ feed 0) ----
            u64 k2 = (lane < NWAVE) ? red[lane] : 0ull;
            k2 = dpp_max16(k2);            // valid in lane 15
            // ---- ONE relaxed agent store publishes the block winner ----
            if (lane == 15) {
                u32 db  = (u32)(k2 >> 32);
                u32 idx = ~(u32)k2;        // = gi (fits 17 bits)
                __hip_atomic_store(&gsp[chunk],
                                   ((u64)db << 32) | ((u64)idx << 15) | (u64)it,
                                   __ATOMIC_RELAXED, __HIP_MEMORY_SCOPE_AGENT);
            }
            // ---- relaxed poll of the 16 slot words (ONE line; r8 protocol) --
            u64 v; bool ok;
            do {
                v  = (lane < NBLK)
                       ? __hip_atomic_load(&gsp[lane], __ATOMIC_RELAXED,
                                           __HIP_MEMORY_SCOPE_AGENT)
                       : 0ull;
                ok = (lane < NBLK) ? ((v & 0x7FFFull) == (u64)it) : true;
            } while (__ballot(ok) != ~0ull);
            u64 k3 = 0ull;
            if (lane < NBLK) {
                u32 db  = (u32)(v >> 32);
                u32 idx = (u32)((v >> 15) & 0x1FFFFu);
                k3 = ((u64)db << 32) | (u64)(~idx);
            }
            k3 = dpp_max16(k3);            // valid in lane 15
            // uniform broadcast via readlane (SGPR): ALL 64 lanes get winner
            u32 widx = ~(u32)__builtin_amdgcn_readlane((int)(u32)k3, 15);
            if (lane == 15) {
                if (chunk == 0) out[b * NSAMP + it] = (int)widx;
                bc = widx;                 // plain store; barrier2 orders it
            }
            // ---- EARLY centroid load (uniform scalar addr): overlaps the
            //      bc-store + barrier2 window; warms per-CU L1 ----
            cx = bxyz[3 * (size_t)widx + 0];
            cy = bxyz[3 * (size_t)widx + 1];
            cz = bxyz[3 * (size_t)widx + 2];
        }
        __syncthreads();                   // barrier2 (orders bc)

        if (w != 0) {
            u32 widx = bc;                 // barrier-ordered plain read
            cx = bxyz[3 * (size_t)widx + 0];   // L1-warm (w0 loaded it)
            cy = bxyz[3 * (size_t)widx + 1];
            cz = bxyz[3 * (size_t)widx + 2];
        }
    }
}

extern "C" void kernel_launch(void* const* d_in, const int* in_sizes, int n_in,
                              void* d_out, int out_size, void* d_ws, size_t ws_size,
                              hipStream_t stream) {
    const float* xyz = (const float*)d_in[0];
    int* out = (int*)d_out;
    u64* gslot = (u64*)d_ws;   // [BATCH][2][NBLK] u64 = 4 KB

    hipLaunchKernelGGL(fps_init_kernel, dim3(1), dim3(512), 0, stream, gslot);
    hipLaunchKernelGGL(fps_kernel, dim3(BATCH * NBLK), dim3(TPB), 0, stream,
                       xyz, out, gslot);
}

// Round 11
// 6810.690 us; speedup vs baseline: 1.0587x; 1.0587x over previous
//
#include <hip/hip_runtime.h>
#include <stdint.h>

// Problem: D-FPS. points_xyz (16, 131072, 3) fp32 -> indices (16, 4096) int32.
//
// Round 25 = round 24 resubmitted verbatim (round 24's bench was an
// infrastructure failure: "MI355X container failed twice", same broker error
// as round 4 which hit the known-safe r18 kernel — no measurement occurred).
//
// Round 24 = round 19 (best: 6871 us) with a DUAL-MODE POLL probing whether
// the slot line can be served by the XCD's shared L2 instead of the chip
// coherence point (MALL). Theory: r19/r20/r21/r23 eliminated dist-DS, reduce
// width, wave count, and the tail load (all dur-neutral) -> the 4100 cy/iter
// is the publish->poll chain; agent-scope atomics on multi-XCD CDNA4 are
// served at the MALL (~600-900 cy RTT, m126), explaining the gap vs a ~1500cy
// L2-based model. All 16 blocks of a batch share blk%8 -> same XCD (perf
// heuristic), vector L1 is write-through, sc0 loads bypass L1 -> the poll MAY
// be L2-servable. FAST PATH: inline-asm global_load_dwordx2 sc0 poll, max 64
// rounds. STICKY FALLBACK: the r8-proven agent-scope poll (byte-identical).
// Correct regardless of placement or agent-store L2 semantics: tag-match on
// a value is valid from any cache level; fast loop is bounded -> no hang.
// Publisher store unchanged (agent). Init stores agent-scope for consistent
// cache state. Everything else byte-identical to r19.
//
// Locked-in lessons (r2-r23):
//  - relaxed-only AGENT atomics for publish; tag in every polled word (r7/r8).
//  - ONE polling wave per block; poll touches ONE cache line (r5/r10/r17).
//  - NARROW fan-in: 16 publishers; no co-residency (r15).
//  - hardware barrier beats software tag-spin intra-block (r13).
//  - DPP (VALU-pipe) reductions, never __shfl chains (r16).
//  - DPP row_bcast does NOT reach lanes below the source row (r22 bug).
//  - phase A AND the post-barrier tail are hidden under the sync chain
//    (r19/r20/r21/r23: four cuts, all dur-neutral or worse).
//  - FMA-chain distance d = fma(dz,dz, fma(dy,dy, dx*dx)), subs exact-rounded
//    (r2: bit-exact vs reference trajectory).
//  - removals help; rearrangements and added traffic regress (r9-r12, r17, r23).

#define BATCH 16
#define NPTS  131072
#define NSAMP 4096
#define NBLK  16                  // blocks per batch
#define TPB   1024                // 16 waves
#define CHUNK (NPTS / NBLK)       // 8192 points per block
#define PPT   (CHUNK / TPB)       // 8 points per thread
#define NWAVE (TPB / 64)
#define FAST_ROUNDS 64            // bounded sc0 probe before sticky fallback

typedef unsigned long long u64;
typedef unsigned int u32;

// ---- DPP 64-bit lexicographic max-reduce helpers --------------------------
// key = dist_bits(32) | ~gi(32): u64 max == (max dist, then min index).
// update_dpp(old=0,...): lanes with no valid source read 0; all real keys
// are > 0, so 0 is the identity.
#define DPP_ROW_SHR(n)  (0x110 | (n))
#define DPP_BCAST15     0x142
#define DPP_BCAST31     0x143

template <int CTRL>
__device__ __forceinline__ u64 dpp_max_step(u64 key) {
    u32 lo = (u32)key, hi = (u32)(key >> 32);
    u32 olo = (u32)__builtin_amdgcn_update_dpp(0, (int)lo, CTRL, 0xF, 0xF, false);
    u32 ohi = (u32)__builtin_amdgcn_update_dpp(0, (int)hi, CTRL, 0xF, 0xF, false);
    u64 o = ((u64)ohi << 32) | (u64)olo;
    return o > key ? o : key;
}

// Full-wave (64 lane) max; result valid in lane 63.
__device__ __forceinline__ u64 dpp_max64(u64 key) {
    key = dpp_max_step<DPP_ROW_SHR(1)>(key);
    key = dpp_max_step<DPP_ROW_SHR(2)>(key);
    key = dpp_max_step<DPP_ROW_SHR(4)>(key);
    key = dpp_max_step<DPP_ROW_SHR(8)>(key);
    key = dpp_max_step<DPP_BCAST15>(key);
    key = dpp_max_step<DPP_BCAST31>(key);
    return key;
}

// Row (16 lane) max over lanes 0..15 (others must hold 0); valid in lane 15.
__device__ __forceinline__ u64 dpp_max16(u64 key) {
    key = dpp_max_step<DPP_ROW_SHR(1)>(key);
    key = dpp_max_step<DPP_ROW_SHR(2)>(key);
    key = dpp_max_step<DPP_ROW_SHR(4)>(key);
    key = dpp_max_step<DPP_ROW_SHR(8)>(key);
    return key;
}

// Global slot word (8B, one per block per parity):
//   [63:32] dist bits (>=0 -> monotone) | [31:15] idx (17b) | [14:0] iter tag
// Poison 0xAA.. -> tag 0x2AAA; zero-init -> tag 0; live tags are 1..4095.
// Ring-2 by parity; ordering via the value-dependence chain (r8-proven).

__global__ void fps_init_kernel(u64* __restrict__ ws) {
    int i = blockIdx.x * blockDim.x + threadIdx.x;
    if (i < BATCH * 2 * NBLK)
        __hip_atomic_store(&ws[i], 0ull, __ATOMIC_RELAXED,
                           __HIP_MEMORY_SCOPE_AGENT);
}

__global__ __launch_bounds__(TPB, 4) void fps_kernel(
        const float* __restrict__ xyz, int* __restrict__ out,
        u64* __restrict__ gslot) {
    const int blk   = blockIdx.x;
    const int b     = blk & 15;    // batch: a batch's 16 blocks share blk%8
    const int chunk = blk >> 4;    //        -> same XCD (round-robin dispatch)
    const int tid   = threadIdx.x;
    const int w     = tid >> 6;
    const int lane  = tid & 63;

    const float* bxyz = xyz + (size_t)b * NPTS * 3;
    const int base = chunk * CHUNK;

    // ---- LDS: SoA points + plain red keys + plain bc (all barrier-ordered) --
    __shared__ float2 sxy[CHUNK];          // 64 KB
    __shared__ float  szz[CHUNK];          // 32 KB
    __shared__ u64 red[NWAVE];
    __shared__ u32 bc;                     // winning index, barrier-ordered
    for (int i = tid; i < CHUNK; i += TPB) {
        size_t p = (size_t)(base + i) * 3;
        sxy[i] = make_float2(bxyz[p + 0], bxyz[p + 1]);
        szz[i] = bxyz[p + 2];
    }
    if (tid == 0 && chunk == 0) out[b * NSAMP] = 0; // iter 0 emits index 0
    __syncthreads();   // staging visibility

    // ---- per-thread 8 loop-invariant points (r19 codegen, best measured) ----
    float px[PPT], py[PPT], pz[PPT], pd[PPT];
#pragma unroll
    for (int k = 0; k < PPT; ++k) {
        int i = tid + TPB * k;
        float2 xy = sxy[i];
        px[k] = xy.x;
        py[k] = xy.y;
        pz[k] = szz[i];
        pd[k] = __builtin_inff();
    }

    float cx = bxyz[0], cy = bxyz[1], cz = bxyz[2];

    u64* gs = gslot + (size_t)b * 2 * NBLK;   // [2][NBLK]

    bool fast_mode = true;   // sticky: sc0/L2 poll until it ever times out

    for (int it = 1; it < NSAMP; ++it) {
        const int par = it & 1;
        u64* gsp = gs + par * NBLK;

        // ---- update min-dists + local argmax (registers) ----
        // Verified arithmetic (round 2, absmax 0): FMA-contracted
        //   d = fma(dz,dz, fma(dy,dy, dx*dx)), subs exact-rounded.
        float bd = -1.0f;
        int   bk = 0;
#pragma unroll
        for (int k = 0; k < PPT; ++k) {
            float dx = __fsub_rn(px[k], cx);
            float dy = __fsub_rn(py[k], cy);
            float dz = __fsub_rn(pz[k], cz);
            float d  = __builtin_fmaf(dz, dz,
                         __builtin_fmaf(dy, dy, __fmul_rn(dx, dx)));
            float nd = fminf(pd[k], d);
            pd[k] = nd;
            // strict >: earliest k wins (gi ascends with k) = first-occurrence
            if (nd > bd) { bd = nd; bk = k; }
        }
        u32 gi = (u32)(base + tid + TPB * bk);
        u64 key = ((u64)__float_as_uint(bd) << 32) | (u64)(~gi);

        // ---- wave max via DPP (VALU pipe) ----
        key = dpp_max64(key);              // valid in lane 63
        if (lane == 63) red[w] = key;      // plain store; barrier1 orders it
        __syncthreads();                   // barrier1

        if (w == 0) {
            // ---- combine 16 plain keys (real keys > 0; lanes 16+ feed 0) ----
            u64 k2 = (lane < NWAVE) ? red[lane] : 0ull;
            k2 = dpp_max16(k2);            // valid in lane 15
            // ---- ONE relaxed agent store publishes the block winner ----
            if (lane == 15) {
                u32 db  = (u32)(k2 >> 32);
                u32 idx = ~(u32)k2;        // = gi (fits 17 bits)
                __hip_atomic_store(&gsp[chunk],
                                   ((u64)db << 32) | ((u64)idx << 15) | (u64)it,
                                   __ATOMIC_RELAXED, __HIP_MEMORY_SCOPE_AGENT);
            }
            // ---- DUAL-MODE POLL --------------------------------------------
            u64 v = 0ull;
            bool done = false;
            if (fast_mode) {
                // FAST: sc0 load = L1-bypass, served by this XCD's L2 (if the
                // agent store updated/filled it). Bounded rounds -> no hang.
                int rounds = 0;
                do {
                    if (lane < NBLK) {
                        u64 a = (u64)(uintptr_t)&gsp[lane];
                        asm volatile(
                            "global_load_dwordx2 %0, %1, off sc0\n\t"
                            "s_waitcnt vmcnt(0)"
                            : "=v"(v) : "v"(a) : "memory");
                    } else v = 0ull;
                    bool ok = (lane < NBLK) ? ((v & 0x7FFFull) == (u64)it)
                                            : true;
                    done = (__ballot(ok) == ~0ull);
                } while (!done && ++rounds < FAST_ROUNDS);
                if (!done) fast_mode = false;   // sticky fallback
            }
            if (!done) {
                // SAFE: byte-identical r8 agent-scope poll (proven).
                bool ok;
                do {
                    v  = (lane < NBLK)
                           ? __hip_atomic_load(&gsp[lane], __ATOMIC_RELAXED,
                                               __HIP_MEMORY_SCOPE_AGENT)
                           : 0ull;
                    ok = (lane < NBLK) ? ((v & 0x7FFFull) == (u64)it) : true;
                } while (__ballot(ok) != ~0ull);
            }
            // ----------------------------------------------------------------
            u64 k3 = 0ull;
            if (lane < NBLK) {
                u32 db  = (u32)(v >> 32);
                u32 idx = (u32)((v >> 15) & 0x1FFFFu);
                k3 = ((u64)db << 32) | (u64)(~idx);
            }
            k3 = dpp_max16(k3);            // valid in lane 15
            if (lane == 15) {
                u32 widx = ~(u32)k3;
                if (chunk == 0) out[b * NSAMP + it] = (int)widx;
                bc = widx;                 // plain store; barrier2 orders it
            }
        }
        __syncthreads();                   // barrier2 (orders bc)

        u32 widx = bc;                     // barrier-ordered plain read
        cx = bxyz[3 * (size_t)widx + 0];   // same-address broadcast load
        cy = bxyz[3 * (size_t)widx + 1];
        cz = bxyz[3 * (size_t)widx + 2];
    }
}

extern "C" void kernel_launch(void* const* d_in, const int* in_sizes, int n_in,
                              void* d_out, int out_size, void* d_ws, size_t ws_size,
                              hipStream_t stream) {
    const float* xyz = (const float*)d_in[0];
    int* out = (int*)d_out;
    u64* gslot = (u64*)d_ws;   // [BATCH][2][NBLK] u64 = 4 KB

    hipLaunchKernelGGL(fps_init_kernel, dim3(1), dim3(512), 0, stream, gslot);
    hipLaunchKernelGGL(fps_kernel, dim3(BATCH * NBLK), dim3(TPB), 0, stream,
                       xyz, out, gslot);
}